// Round 12
// baseline (293.886 us; speedup 1.0000x reference)
//
#include <hip/hip_runtime.h>
#include <hip/hip_cooperative_groups.h>
#include <hip/hip_bf16.h>
#include <hip/hip_fp8.h>
#include <hip/hip_fp16.h>

namespace cg = cooperative_groups;

#define N_NODESC 100000
#define N_EDGESC 1600000
#define FEATC 64
#define BATCHC 64
#define MAXLENC 2048
#define NBLK 250           // cooperative grid: 1 block/CU guaranteed (<=256)
#define NBUCK 500          // 500 buckets x 200 dst nodes
#define BSZ 200
#define NPB 400            // nodes transformed per block (250*400 = 100000)
#define EPB 6400           // edge slice per block (250*6400 = 1.6M)
#define CAP 6144           // LDS edge capacity per bucket (mean 3200)

__device__ __forceinline__ float b2f(unsigned short u){
  union { unsigned u; float f; } c; c.u = ((unsigned)u) << 16; return c.f;
}
__device__ __forceinline__ unsigned short f2b(float f){
  union { float f; unsigned u; } c; c.f = f;
  unsigned r = c.u + 0x7fffu + ((c.u >> 16) & 1u);
  return (unsigned short)(r >> 16);
}
__device__ __forceinline__ int clampi(int v, int lo, int hi){
  return v < lo ? lo : (v > hi ? hi : v);
}
__device__ __forceinline__ void unpack8(uint4 v, float* o){
  o[0] = b2f((unsigned short)(v.x & 0xffff)); o[1] = b2f((unsigned short)(v.x >> 16));
  o[2] = b2f((unsigned short)(v.y & 0xffff)); o[3] = b2f((unsigned short)(v.y >> 16));
  o[4] = b2f((unsigned short)(v.z & 0xffff)); o[5] = b2f((unsigned short)(v.z >> 16));
  o[6] = b2f((unsigned short)(v.w & 0xffff)); o[7] = b2f((unsigned short)(v.w >> 16));
}
__device__ __forceinline__ float fp8tof(unsigned char b){
  __hip_fp8_e4m3 q; q.__x = (__hip_fp8_storage_t)b; return (float)q;
}

union U1u {
  float Wsf[4096];                                          // P1 (16 KB)
  struct { unsigned sorted[EPB]; unsigned short sbk[EPB]; } s2;  // P2 (38.4 KB)
};

// inclusive scan of arr[0..511] in LDS; wave-intrinsic, 3 barriers
__device__ __forceinline__ void scan512(int* arr, int* part, int t){
  int w = t >> 6, l = t & 63;
  if (t < 512) {
    int v = arr[t];
    #pragma unroll
    for (int off = 1; off < 64; off <<= 1) {
      int n = __shfl_up(v, off, 64);
      if (l >= off) v += n;
    }
    arr[t] = v;
    if (l == 63) part[w] = v;
  }
  __syncthreads();
  if (t < 8) {
    int p = part[t];
    #pragma unroll
    for (int off = 1; off < 8; off <<= 1) {
      int n = __shfl_up(p, off, 8);
      if (t >= off) p += n;
    }
    part[t] = p;
  }
  __syncthreads();
  if (t < 512 && w > 0) arr[t] += part[w - 1];
  __syncthreads();
}

__global__ __launch_bounds__(1024, 4) void k_fused(
    const unsigned short* __restrict__ x, const unsigned short* __restrict__ W,
    const unsigned short* __restrict__ attS, const unsigned short* __restrict__ attD,
    const unsigned short* __restrict__ bias,
    const int* __restrict__ ei, const int* __restrict__ traj, const int* __restrict__ lens,
    unsigned char* __restrict__ xw8, __half* __restrict__ a_srch, float* __restrict__ a_dst,
    int* __restrict__ cc, int* __restrict__ gcur, unsigned* __restrict__ cs,
    unsigned short* __restrict__ nembh, float* __restrict__ out)
{
  __shared__ U1u U1;                 // 38.4 KB (Wsf in P1; sorted/sbk in P2)
  __shared__ int buf[9600];          // 38.4 KB: pk[6400] + bk ushort[6400]; ssrc in P3
  __shared__ int hh[512], lcur[512], bst[512], gbv[512];   // 8 KB
  __shared__ int part[16];
  __shared__ float as_s[64], ad_s[64];

  int t = threadIdx.x;
  int blk = blockIdx.x;
  cg::grid_group grid = cg::this_grid();

  // ---- P0: zero global counters ----
  if (blk == 0) {
    if (t < 512) cc[t] = 0; else gcur[t - 512] = 0;
  }
  grid.sync();

  // ---- P1: stage W; edge slice -> LDS + global hist; node transform ----
  for (int i = t; i < 4096; i += 1024) U1.Wsf[i] = b2f(W[i]);
  if (t < 64) { as_s[t] = b2f(attS[t]); ad_s[t] = b2f(attD[t]); }
  if (t < 512) hh[t] = 0;
  __syncthreads();

  unsigned* pk = (unsigned*)buf;
  unsigned short* bkus = (unsigned short*)(buf + EPB);
  int ebase = blk * EPB;
  for (int i = t; i < EPB; i += 1024) {
    int s = clampi(ei[ebase + i], 0, N_NODESC - 1);
    int d = clampi(ei[N_EDGESC + ebase + i], 0, N_NODESC - 1);
    int b = d / BSZ;
    pk[i] = (unsigned)s | ((unsigned)(d - b * BSZ) << 17);
    bkus[i] = (unsigned short)b;
    atomicAdd(&hh[b], 1);
  }

  if (t < 400) {
    int g = t & 3, quad = t >> 2;
    const float4* Ws4 = (const float4*)U1.Wsf;
    #pragma unroll
    for (int pass = 0; pass < 2; pass++) {
      int n0 = blk * NPB + quad * 4 + pass * 2;
      float acc[2][16];
      #pragma unroll
      for (int j = 0; j < 2; j++)
        #pragma unroll
        for (int c = 0; c < 16; c++) acc[j][c] = 0.f;
      for (int i = 0; i < 8; i++) {
        float xu[2][8];
        #pragma unroll
        for (int j = 0; j < 2; j++) {
          uint4 v = ((const uint4*)(x + (size_t)(n0 + j) * 64))[i];
          unpack8(v, xu[j]);
        }
        #pragma unroll
        for (int u = 0; u < 8; u++) {
          int k = i * 8 + u;
          float4 w0 = Ws4[k * 16 + g * 4 + 0];
          float4 w1 = Ws4[k * 16 + g * 4 + 1];
          float4 w2 = Ws4[k * 16 + g * 4 + 2];
          float4 w3 = Ws4[k * 16 + g * 4 + 3];
          #pragma unroll
          for (int j = 0; j < 2; j++) {
            float xk = xu[j][u];
            acc[j][ 0] += xk * w0.x; acc[j][ 1] += xk * w0.y;
            acc[j][ 2] += xk * w0.z; acc[j][ 3] += xk * w0.w;
            acc[j][ 4] += xk * w1.x; acc[j][ 5] += xk * w1.y;
            acc[j][ 6] += xk * w1.z; acc[j][ 7] += xk * w1.w;
            acc[j][ 8] += xk * w2.x; acc[j][ 9] += xk * w2.y;
            acc[j][10] += xk * w2.z; acc[j][11] += xk * w2.w;
            acc[j][12] += xk * w3.x; acc[j][13] += xk * w3.y;
            acc[j][14] += xk * w3.z; acc[j][15] += xk * w3.w;
          }
        }
      }
      #pragma unroll
      for (int j = 0; j < 2; j++) {
        int n = n0 + j;
        union { unsigned u[4]; unsigned char b[16]; } pq;
        #pragma unroll
        for (int c = 0; c < 16; c++)
          pq.b[c] = (unsigned char)__hip_fp8_e4m3(acc[j][c]).__x;
        uint4 o; o.x = pq.u[0]; o.y = pq.u[1]; o.z = pq.u[2]; o.w = pq.u[3];
        *((uint4*)(xw8 + (size_t)n * 64 + g * 16)) = o;
        #pragma unroll
        for (int hl = 0; hl < 2; hl++) {
          int h = g * 2 + hl;
          float sa = 0.f, sd = 0.f;
          #pragma unroll
          for (int c = 0; c < 8; c++) {
            sa += acc[j][hl * 8 + c] * as_s[h * 8 + c];
            sd += acc[j][hl * 8 + c] * ad_s[h * 8 + c];
          }
          a_srch[n * 8 + h] = __float2half(sa);
          a_dst[n * 8 + h] = sd;
        }
      }
    }
  }
  grid.sync();   // cc complete; tables complete

  // ---- P2: scans + LDS counting-sort of slice + run-contiguous cs write ----
  int ccj = 0, myh = 0;
  if (t < 512) {
    ccj = cc[t]; bst[t] = ccj;
    myh = hh[t]; gbv[t] = myh;
  }
  __syncthreads();
  scan512(bst, part, t);                 // inclusive scan of cc
  scan512(gbv, part, t);                 // inclusive scan of local hist
  if (t < 512) {
    bst[t] -= ccj;                       // exclusive global bucket start (keep thru P3)
    int lst_ = gbv[t] - myh;             // local exclusive
    hh[t] = lst_;
    lcur[t] = lst_;
    gbv[t] = myh ? atomicAdd(&gcur[t], myh) : 0;   // this block's run offset in bucket
  }
  __syncthreads();
  for (int i = t; i < EPB; i += 1024) {
    int b = bkus[i];
    int p = atomicAdd(&lcur[b], 1);
    U1.s2.sorted[p] = pk[i];
    U1.s2.sbk[p] = (unsigned short)b;
  }
  __syncthreads();
  for (int i = t; i < EPB; i += 1024) {
    int b = U1.s2.sbk[i];
    cs[bst[b] + gbv[b] + (i - hh[b])] = U1.s2.sorted[i];
  }
  grid.sync();   // cs complete

  // ---- P3: per-bucket aggregation (2 buckets per block, sequential) ----
  int* ssrc = buf;   // alias (pk/bkus dead)
  int wv = t >> 6, l = t & 63, H = l >> 3, hw = l & 7;
  for (int half = 0; half < 2; half++) {
    int bu = blk * 2 + half;
    int base = bst[bu];
    int cnt  = cc[bu];
    int scnt = cnt < CAP ? cnt : CAP;
    if (t < 256) hh[t] = 0;              // hh = lcnt
    __syncthreads();
    unsigned ce[6];
    #pragma unroll
    for (int j = 0; j < 6; j++) {
      int i = t + j * 1024;
      if (i < scnt) { ce[j] = cs[base + i]; atomicAdd(&hh[ce[j] >> 17], 1); }
    }
    __syncthreads();
    if (t < 512) gbv[t] = (t < 256) ? hh[t] : 0;
    __syncthreads();
    scan512(gbv, part, t);
    if (t < 256) { int ex = gbv[t] - hh[t]; gbv[t] = ex; lcur[t] = ex; }  // gbv = loff
    __syncthreads();
    #pragma unroll
    for (int j = 0; j < 6; j++) {
      int i = t + j * 1024;
      if (i < scnt) {
        int p = atomicAdd(&lcur[ce[j] >> 17], 1);
        ssrc[p] = (int)(ce[j] & 0x1FFFFu);
      }
    }
    __syncthreads();

    for (int dl = wv; dl < BSZ; dl += 16) {
      int dst = bu * BSZ + dl;
      float adH = a_dst[dst * 8 + H];
      float zs  = __half2float(a_srch[dst * 8 + H]) + adH;
      float selfw = __expf(fmaxf(zs, 0.2f * zs));
      float acc = selfw * fp8tof(xw8[(size_t)dst * 64 + l]);
      float adW = a_dst[dst * 8 + hw];

      int beg = gbv[dl];
      int end2 = beg + hh[dl];
      float lw = 0.f, lw2 = 0.f;

      for (int i = beg; i < end2; i += 8) {
        int idx = i + H;
        bool valid = idx < end2;
        int sv = ssrc[valid ? idx : end2 - 1];
        float av = __half2float(a_srch[sv * 8 + hw]);
        float z = av + adW;
        float w = __expf(fmaxf(z, 0.2f * z));
        w = valid ? w : 0.f;
        lw += w;
        #pragma unroll
        for (int e = 0; e < 8; e++) {
          int   se = __builtin_amdgcn_readlane(sv, e * 8);
          float wb = __shfl(w, (e << 3) + H, 64);
          float xv = fp8tof(xw8[(size_t)se * 64 + l]);
          acc += wb * xv;
        }
      }

      // overflow beyond LDS capacity (statistically never taken)
      for (int i = CAP; i < cnt; i++) {
        unsigned e = cs[base + i];
        if ((int)(e >> 17) != dl) continue;
        int sv = (int)(e & 0x1FFFFu);
        float zz = __half2float(a_srch[sv * 8 + H]) + adH;
        float w = __expf(fmaxf(zz, 0.2f * zz));
        lw2 += w;
        acc += w * fp8tof(xw8[(size_t)sv * 64 + l]);
      }

      lw += __shfl_xor(lw, 8, 64);
      lw += __shfl_xor(lw, 16, 64);
      lw += __shfl_xor(lw, 32, 64);
      float denom = selfw + __shfl(lw, H, 64) + lw2;

      float v = acc / denom + b2f(bias[l]);
      nembh[(size_t)dst * 64 + l] = f2b(v > 0.f ? v : 0.f);
    }
    __syncthreads();
  }
  grid.sync();   // nembh complete

  // ---- P4: padded gather (fp32 out) + seq_lengths tail ----
  const int NCH = BATCHC * MAXLENC * 16;
  int gstride = NBLK * 1024;
  for (int cid = blk * 1024 + t; cid < NCH; cid += gstride) {
    int b = cid >> 15;
    int rem = cid & 32767;
    int sl = rem >> 4;
    int ch = rem & 15;
    int len = clampi(lens[b], 0, MAXLENC);
    float4 val = make_float4(0.f, 0.f, 0.f, 0.f);
    if (sl < len) {
      int node = clampi(traj[b * MAXLENC + sl], 0, N_NODESC - 1);
      uint2 q = ((const uint2*)nembh)[(size_t)node * 16 + ch];
      val = make_float4(b2f((unsigned short)(q.x & 0xffff)),
                        b2f((unsigned short)(q.x >> 16)),
                        b2f((unsigned short)(q.y & 0xffff)),
                        b2f((unsigned short)(q.y >> 16)));
    }
    ((float4*)out)[cid] = val;
  }
  int g0 = blk * 1024 + t;
  if (g0 < BATCHC) out[(size_t)BATCHC * MAXLENC * FEATC + g0] = (float)lens[g0];
}

extern "C" void kernel_launch(void* const* d_in, const int* in_sizes, int n_in,
                              void* d_out, int out_size, void* d_ws, size_t ws_size,
                              hipStream_t stream) {
  const unsigned short* x    = (const unsigned short*)d_in[0];
  const unsigned short* W    = (const unsigned short*)d_in[1];
  const unsigned short* attS = (const unsigned short*)d_in[2];
  const unsigned short* attD = (const unsigned short*)d_in[3];
  const unsigned short* bias = (const unsigned short*)d_in[4];
  const int* ei   = (const int*)d_in[5];
  const int* traj = (const int*)d_in[6];
  const int* lens = (const int*)d_in[7];
  float* out = (float*)d_out;

  // workspace (float units, max 9.9M floats = 39.6 MB; under proven size):
  //  [0, 1.6M)        xw fp8 (6.4M bytes)
  //  [3.2M, 3.6M)     a_src fp16 (800k half)
  //  [4.0M, 4.8M)     a_dst fp32
  //  [4.9M, +512)     cc (512 ints)      (zeroed in-kernel P0)
  //  [+512, +1024)    gcur (512 ints)
  //  [5.0M, 6.6M)     cs (packed uint, 1.6M)
  //  [6.7M, 9.9M)     nemb bf16 (6.4M ushort)
  float* F = (float*)d_ws;
  unsigned char* xw8 = (unsigned char*)d_ws;
  __half* a_srch = (__half*)(F + 3200000);
  float* a_dst   = F + 4000000;
  int* cc        = (int*)(F + 4900000);
  int* gcur      = (int*)(F + 4900000) + 512;
  unsigned* cs   = (unsigned*)(F + 5000000);
  unsigned short* nembh = (unsigned short*)(F + 6700000);

  void* args[] = {
    (void*)&x, (void*)&W, (void*)&attS, (void*)&attD, (void*)&bias,
    (void*)&ei, (void*)&traj, (void*)&lens,
    (void*)&xw8, (void*)&a_srch, (void*)&a_dst,
    (void*)&cc, (void*)&gcur, (void*)&cs, (void*)&nembh, (void*)&out
  };
  hipLaunchCooperativeKernel((const void*)k_fused, dim3(NBLK), dim3(1024),
                             args, 0, stream);
}

// Round 13
// 211.598 us; speedup vs baseline: 1.3889x; 1.3889x over previous
//
#include <hip/hip_runtime.h>
#include <hip/hip_bf16.h>
#include <hip/hip_fp16.h>

#define N_NODESC 100000
#define N_EDGESC 1600000
#define FEATC 64
#define BATCHC 64
#define MAXLENC 2048
#define NBUCK 500          // 500 buckets x exactly 200 dst nodes
#define BSZ 200
#define CAP 6144           // LDS edge capacity per bucket (mean 3200)
#define P3_EDGES 8192      // edges per k_csort workgroup (1024 thr x 8)
#define K1B 391            // k_pre blocks doing the node transform

__device__ __forceinline__ float b2f(unsigned short u){
  union { unsigned u; float f; } c; c.u = ((unsigned)u) << 16; return c.f;
}
__device__ __forceinline__ unsigned short f2b(float f){
  union { float f; unsigned u; } c; c.f = f;
  unsigned r = c.u + 0x7fffu + ((c.u >> 16) & 1u);
  return (unsigned short)(r >> 16);
}
__device__ __forceinline__ int clampi(int v, int lo, int hi){
  return v < lo ? lo : (v > hi ? hi : v);
}
__device__ __forceinline__ void unpack8(uint4 v, float* o){
  o[0] = b2f((unsigned short)(v.x & 0xffff)); o[1] = b2f((unsigned short)(v.x >> 16));
  o[2] = b2f((unsigned short)(v.y & 0xffff)); o[3] = b2f((unsigned short)(v.y >> 16));
  o[4] = b2f((unsigned short)(v.z & 0xffff)); o[5] = b2f((unsigned short)(v.z >> 16));
  o[6] = b2f((unsigned short)(v.w & 0xffff)); o[7] = b2f((unsigned short)(v.w >> 16));
}
// fp4 e2m1 encode: representable magnitudes {0,0.5,1,1.5,2,3,4,6}
__device__ __forceinline__ unsigned f2fp4(float v){
  unsigned s = (__float_as_uint(v) >> 31) << 3;
  float q = fabsf(v);
  int c = (q > 0.25f) + (q > 0.75f) + (q > 1.25f) + (q > 1.75f)
        + (q > 2.5f) + (q > 3.5f) + (q > 5.0f);
  return s | (unsigned)c;
}

// ---- K_pre: heterogeneous grid. Blocks [0,K1B): xw=x@W -> fp4 + a_src(fp16)
// + a_dst(fp32). Blocks [K1B,..): coarse 500-bin histogram of dst. ----
__global__ __launch_bounds__(256) void k_pre(
    const unsigned short* __restrict__ x, const unsigned short* __restrict__ W,
    const unsigned short* __restrict__ attS, const unsigned short* __restrict__ attD,
    const int* __restrict__ ei,
    unsigned char* __restrict__ xw4, __half* __restrict__ a_srch,
    float* __restrict__ a_dst, int* __restrict__ cc)
{
  __shared__ float Wsf[64 * 64];
  __shared__ float as_s[64];
  __shared__ float ad_s[64];
  __shared__ int hh[NBUCK];
  int t = threadIdx.x;

  if (blockIdx.x >= K1B) {
    for (int i = t; i < NBUCK; i += 256) hh[i] = 0;
    __syncthreads();
    int g = (blockIdx.x - K1B) * 256 + t;
    if (g < N_EDGESC / 4) {
      int4 d = ((const int4*)(ei + N_EDGESC))[g];
      atomicAdd(&hh[clampi(d.x, 0, N_NODESC - 1) / BSZ], 1);
      atomicAdd(&hh[clampi(d.y, 0, N_NODESC - 1) / BSZ], 1);
      atomicAdd(&hh[clampi(d.z, 0, N_NODESC - 1) / BSZ], 1);
      atomicAdd(&hh[clampi(d.w, 0, N_NODESC - 1) / BSZ], 1);
    }
    __syncthreads();
    for (int i = t; i < NBUCK; i += 256) if (hh[i]) atomicAdd(&cc[i], hh[i]);
    return;
  }

  for (int i = t; i < 4096; i += 256) Wsf[i] = b2f(W[i]);
  if (t < 64) { as_s[t] = b2f(attS[t]); ad_s[t] = b2f(attD[t]); }
  __syncthreads();

  int g    = t & 3;          // col group: chans g*16..g*16+15
  int slot = t >> 2;
  int n0 = blockIdx.x * 256 + slot * 4;

  float acc[4][16];
  #pragma unroll
  for (int j = 0; j < 4; j++)
    #pragma unroll
    for (int c = 0; c < 16; c++) acc[j][c] = 0.f;

  const float4* Ws4 = (const float4*)Wsf;
  for (int i = 0; i < 8; i++) {
    float xu[4][8];
    #pragma unroll
    for (int j = 0; j < 4; j++) {
      int n = n0 + j;
      uint4 v = make_uint4(0u,0u,0u,0u);
      if (n < N_NODESC) v = ((const uint4*)(x + (size_t)n * 64))[i];
      unpack8(v, xu[j]);
    }
    #pragma unroll
    for (int u = 0; u < 8; u++) {
      int k = i * 8 + u;
      float4 w0 = Ws4[k * 16 + g * 4 + 0];
      float4 w1 = Ws4[k * 16 + g * 4 + 1];
      float4 w2 = Ws4[k * 16 + g * 4 + 2];
      float4 w3 = Ws4[k * 16 + g * 4 + 3];
      #pragma unroll
      for (int j = 0; j < 4; j++) {
        float xk = xu[j][u];
        acc[j][ 0] += xk * w0.x; acc[j][ 1] += xk * w0.y;
        acc[j][ 2] += xk * w0.z; acc[j][ 3] += xk * w0.w;
        acc[j][ 4] += xk * w1.x; acc[j][ 5] += xk * w1.y;
        acc[j][ 6] += xk * w1.z; acc[j][ 7] += xk * w1.w;
        acc[j][ 8] += xk * w2.x; acc[j][ 9] += xk * w2.y;
        acc[j][10] += xk * w2.z; acc[j][11] += xk * w2.w;
        acc[j][12] += xk * w3.x; acc[j][13] += xk * w3.y;
        acc[j][14] += xk * w3.z; acc[j][15] += xk * w3.w;
      }
    }
  }

  #pragma unroll
  for (int j = 0; j < 4; j++) {
    int n = n0 + j;
    if (n >= N_NODESC) break;
    // pack 16 chans -> 8 fp4-pair bytes (byte k = chan 2k | chan 2k+1 << 4)
    union { unsigned u[2]; unsigned char b[8]; } pq;
    #pragma unroll
    for (int c = 0; c < 8; c++)
      pq.b[c] = (unsigned char)(f2fp4(acc[j][2*c]) | (f2fp4(acc[j][2*c+1]) << 4));
    *((uint2*)(xw4 + (size_t)n * 32 + g * 8)) = make_uint2(pq.u[0], pq.u[1]);

    #pragma unroll
    for (int hl = 0; hl < 2; hl++) {
      int h = g * 2 + hl;
      float sa = 0.f, sd = 0.f;
      #pragma unroll
      for (int c = 0; c < 8; c++) {
        sa += acc[j][hl * 8 + c] * as_s[h * 8 + c];
        sd += acc[j][hl * 8 + c] * ad_s[h * 8 + c];
      }
      a_srch[n * 8 + h] = __float2half(sa);
      a_dst[n * 8 + h] = sd;
    }
  }
}

// ---- coarse scatter (1024 thr, 8192 edges/wg): self-scan of cc -> bstart,
// LDS counting-sort by bucket, contiguous run writes via zero-based gcur ----
__global__ __launch_bounds__(1024) void k_csort(const int* __restrict__ ei,
                                                const int* __restrict__ cc,
                                                int* __restrict__ gcur,
                                                unsigned* __restrict__ cs) {
  __shared__ int bst[512];
  __shared__ int h[NBUCK], lst[NBUCK], lcur[NBUCK], gb[NBUCK];
  __shared__ int sc[512];
  __shared__ unsigned sorted[P3_EDGES];
  __shared__ unsigned short sbk[P3_EDGES];
  int t = threadIdx.x;
  int base = blockIdx.x * P3_EDGES;
  for (int i = t; i < NBUCK; i += 1024) h[i] = 0;
  int myc = 0;
  if (t < 512) { myc = (t < NBUCK) ? cc[t] : 0; bst[t] = myc; }
  __syncthreads();
  for (int off = 1; off < 512; off <<= 1) {
    int v = 0;
    if (t < 512) { v = bst[t]; if (t >= off) v += bst[t - off]; }
    __syncthreads();
    if (t < 512) bst[t] = v;
    __syncthreads();
  }
  unsigned pk[8]; int bk[8];
  #pragma unroll
  for (int k = 0; k < 8; k++) {
    int idx = base + k * 1024 + t;
    bk[k] = -1;
    if (idx < N_EDGESC) {
      int s = clampi(ei[idx], 0, N_NODESC - 1);
      int d = clampi(ei[N_EDGESC + idx], 0, N_NODESC - 1);
      int b = d / BSZ;
      pk[k] = (unsigned)s | ((unsigned)(d - b * BSZ) << 17);
      bk[k] = b;
      atomicAdd(&h[b], 1);
    }
  }
  __syncthreads();
  if (t < 512) sc[t] = (t < NBUCK) ? h[t] : 0;
  __syncthreads();
  for (int off = 1; off < 512; off <<= 1) {
    int v = 0;
    if (t < 512) { v = sc[t]; if (t >= off) v += sc[t - off]; }
    __syncthreads();
    if (t < 512) sc[t] = v;
    __syncthreads();
  }
  if (t < NBUCK) {
    int ex = sc[t] - h[t];
    lst[t] = ex; lcur[t] = ex;
    if (h[t]) gb[t] = (bst[t] - myc) + atomicAdd(&gcur[t], h[t]);
  }
  __syncthreads();
  #pragma unroll
  for (int k = 0; k < 8; k++) if (bk[k] >= 0) {
    int p = atomicAdd(&lcur[bk[k]], 1);
    sorted[p] = pk[k];
    sbk[p] = (unsigned short)bk[k];
  }
  __syncthreads();
  int cnt = N_EDGESC - base; if (cnt > P3_EDGES) cnt = P3_EDGES;
  #pragma unroll
  for (int k = 0; k < 8; k++) {
    int i = k * 1024 + t;
    if (i < cnt) {
      int b = sbk[i];
      cs[gb[b] + (i - lst[b])] = sorted[i];
    }
  }
}

// ---- K_aggf: one 1024-thread WG per bucket (200 dsts). Self-scans cc;
// counting-sorts its edges into LDS; per-dst wave aggregation with fp4
// messages decoded via register-LUT shfl. ----
__global__ __launch_bounds__(1024) void k_aggf(
    const __half* __restrict__ a_srch, const float* __restrict__ a_dst,
    const unsigned char* __restrict__ xw4, const unsigned* __restrict__ cs,
    const int* __restrict__ cc,
    const unsigned short* __restrict__ bias, unsigned short* __restrict__ nembh)
{
  __shared__ int bsc[512];
  __shared__ int lcnt[256], loff[256], lcur[256];
  __shared__ int ssrc[CAP];
  __shared__ int sbase, scnt0;
  int t = threadIdx.x;
  int b = blockIdx.x;

  int myc = 0;
  if (t < 512) { myc = (t < NBUCK) ? cc[t] : 0; bsc[t] = myc; }
  __syncthreads();
  for (int off = 1; off < 512; off <<= 1) {
    int v = 0;
    if (t < 512) { v = bsc[t]; if (t >= off) v += bsc[t - off]; }
    __syncthreads();
    if (t < 512) bsc[t] = v;
    __syncthreads();
  }
  if (t == b) { sbase = bsc[t] - myc; scnt0 = myc; }
  if (t < 256) lcnt[t] = 0;
  __syncthreads();
  int base = sbase;
  int cnt  = scnt0;
  int scnt = cnt < CAP ? cnt : CAP;

  unsigned ce[6];
  #pragma unroll
  for (int j = 0; j < 6; j++) {
    int i = t + j * 1024;
    if (i < scnt) { ce[j] = cs[base + i]; atomicAdd(&lcnt[ce[j] >> 17], 1); }
  }
  __syncthreads();
  if (t < 256) loff[t] = lcnt[t];
  __syncthreads();
  for (int off = 1; off < 256; off <<= 1) {
    int v = 0;
    if (t < 256) { v = loff[t]; if (t >= off) v += loff[t - off]; }
    __syncthreads();
    if (t < 256) loff[t] = v;
    __syncthreads();
  }
  if (t < 256) { int ex = loff[t] - lcnt[t]; loff[t] = ex; lcur[t] = ex; }
  __syncthreads();
  #pragma unroll
  for (int j = 0; j < 6; j++) {
    int i = t + j * 1024;
    if (i < scnt) {
      int p = atomicAdd(&lcur[ce[j] >> 17], 1);
      ssrc[p] = (int)(ce[j] & 0x1FFFFu);
    }
  }
  __syncthreads();

  int wv = t >> 6;
  int l  = t & 63;
  int H  = l >> 3;
  int hw = l & 7;

  // per-lane fp4 decode LUT: lane (l&48)|c holds value of code c (c = l&15)
  int c15 = l & 15;
  int m3 = c15 & 7;
  float mag = (m3 < 2) ? 0.5f * (float)m3
            : (1.0f + 0.5f * (float)(m3 & 1)) * (float)(1 << ((m3 >> 1) - 1));
  float lutv = (c15 & 8) ? -mag : mag;
  int lgrp = l & 48;
  int mybyte = l >> 1;
  int odd = l & 1;

  for (int dl = wv; dl < BSZ; dl += 16) {
    int dst = b * BSZ + dl;
    float adH = a_dst[dst * 8 + H];
    float zs  = __half2float(a_srch[dst * 8 + H]) + adH;
    float selfw = __expf(fmaxf(zs, 0.2f * zs));
    unsigned sb0 = xw4[(size_t)dst * 32 + mybyte];
    int nib0 = odd ? (sb0 >> 4) : (sb0 & 15);
    float acc = selfw * __shfl(lutv, lgrp | nib0, 64);
    float adW = a_dst[dst * 8 + hw];

    int beg = loff[dl];
    int end2 = beg + lcnt[dl];
    float lw = 0.f, lw2 = 0.f;

    for (int i = beg; i < end2; i += 8) {
      int idx = i + H;
      bool valid = idx < end2;
      int sv = ssrc[valid ? idx : end2 - 1];
      float av = __half2float(a_srch[sv * 8 + hw]);
      float z = av + adW;
      float w = __expf(fmaxf(z, 0.2f * z));
      w = valid ? w : 0.f;
      lw += w;
      #pragma unroll
      for (int e = 0; e < 8; e++) {
        int   se = __builtin_amdgcn_readlane(sv, e * 8);
        float wb = __shfl(w, (e << 3) + H, 64);
        unsigned by = xw4[(size_t)se * 32 + mybyte];
        int nib = odd ? (by >> 4) : (by & 15);
        float xv = __shfl(lutv, lgrp | nib, 64);
        acc += wb * xv;
      }
    }

    // overflow beyond LDS capacity (statistically never taken)
    for (int i = CAP; i < cnt; i++) {
      unsigned e = cs[base + i];
      if ((int)(e >> 17) != dl) continue;
      int sv = (int)(e & 0x1FFFFu);
      float zz = __half2float(a_srch[sv * 8 + H]) + adH;
      float w = __expf(fmaxf(zz, 0.2f * zz));
      lw2 += w;
      unsigned by = xw4[(size_t)sv * 32 + mybyte];
      int nib = odd ? (by >> 4) : (by & 15);
      acc += w * __shfl(lutv, lgrp | nib, 64);
    }

    lw += __shfl_xor(lw, 8, 64);
    lw += __shfl_xor(lw, 16, 64);
    lw += __shfl_xor(lw, 32, 64);
    float denom = selfw + __shfl(lw, H, 64) + lw2;

    float v = acc / denom + b2f(bias[l]);
    nembh[(size_t)dst * 64 + l] = f2b(v > 0.f ? v : 0.f);
  }
}

// ---- K6: padded gather from bf16 nemb -> fp32 out + seq_lengths tail ----
__global__ __launch_bounds__(256) void k6_gather(
    const unsigned short* __restrict__ nembh, const int* __restrict__ traj,
    const int* __restrict__ lens, float* __restrict__ out)
{
  int gid = blockIdx.x * 256 + threadIdx.x;
  if (gid < BATCHC * MAXLENC * 16) {
    int b = gid >> 15;
    int rem = gid & 32767;
    int l = rem >> 4;
    int ch = rem & 15;
    int len = clampi(lens[b], 0, MAXLENC);
    float4 val = make_float4(0.f, 0.f, 0.f, 0.f);
    if (l < len) {
      int node = clampi(traj[b * MAXLENC + l], 0, N_NODESC - 1);
      uint2 q = ((const uint2*)nembh)[(size_t)node * 16 + ch];
      val = make_float4(b2f((unsigned short)(q.x & 0xffff)),
                        b2f((unsigned short)(q.x >> 16)),
                        b2f((unsigned short)(q.y & 0xffff)),
                        b2f((unsigned short)(q.y >> 16)));
    }
    ((float4*)out)[gid] = val;
  }
  if (gid < BATCHC) {
    out[(size_t)BATCHC * MAXLENC * FEATC + gid] = (float)lens[gid];
  }
}

extern "C" void kernel_launch(void* const* d_in, const int* in_sizes, int n_in,
                              void* d_out, int out_size, void* d_ws, size_t ws_size,
                              hipStream_t stream) {
  const unsigned short* x    = (const unsigned short*)d_in[0];
  const unsigned short* W    = (const unsigned short*)d_in[1];
  const unsigned short* attS = (const unsigned short*)d_in[2];
  const unsigned short* attD = (const unsigned short*)d_in[3];
  const unsigned short* bias = (const unsigned short*)d_in[4];
  const int* ei   = (const int*)d_in[5];
  const int* traj = (const int*)d_in[6];
  const int* lens = (const int*)d_in[7];
  float* out = (float*)d_out;

  // workspace (float units, max 9.9M floats = 39.6 MB):
  //  [0, 0.8M)        xw fp4 (3.2M bytes)
  //  [3.2M, 3.6M)     a_src fp16 (800k half)
  //  [4.0M, 4.8M)     a_dst fp32
  //  [4.9M, +512)     cc (500)
  //  [+512, +1024)    gcur (500, zero-based)   -- one memset covers both
  //  [5.0M, 6.6M)     cs (packed uint, 1.6M)
  //  [6.7M, 9.9M)     nemb bf16 (6.4M ushort)
  float* F = (float*)d_ws;
  unsigned char* xw4 = (unsigned char*)d_ws;
  __half* a_srch = (__half*)(F + 3200000);
  float* a_dst   = F + 4000000;
  int* ccounts   = (int*)(F + 4900000);
  int* gcur      = (int*)(F + 4900000) + 512;
  unsigned* cs   = (unsigned*)(F + 5000000);
  unsigned short* nembh = (unsigned short*)(F + 6700000);

  hipMemsetAsync(ccounts, 0, 1024 * sizeof(int), stream);
  k_pre<<<K1B + (N_EDGESC / 4 + 255) / 256, 256, 0, stream>>>(
      x, W, attS, attD, ei, xw4, a_srch, a_dst, ccounts);
  k_csort<<<(N_EDGESC + P3_EDGES - 1) / P3_EDGES, 1024, 0, stream>>>(ei, ccounts, gcur, cs);
  k_aggf<<<NBUCK, 1024, 0, stream>>>(a_srch, a_dst, xw4, cs, ccounts, bias, nembh);
  k6_gather<<<(BATCHC * MAXLENC * 16 + 255) / 256, 256, 0, stream>>>(nembh, traj, lens, out);
}

// Round 14
// 209.978 us; speedup vs baseline: 1.3996x; 1.0077x over previous
//
#include <hip/hip_runtime.h>
#include <hip/hip_bf16.h>
#include <hip/hip_fp8.h>
#include <hip/hip_fp16.h>

#define N_NODESC 100000
#define N_EDGESC 1600000
#define FEATC 64
#define BATCHC 64
#define MAXLENC 2048
#define NBUCK 500          // 500 buckets x exactly 200 dst nodes
#define BSZ 200
#define CAP 6144           // LDS edge capacity per bucket (mean 3200)
#define P3_EDGES 8192      // edges per k_csort workgroup (1024 thr x 8)
#define K1B 391            // k_pre blocks doing the node transform

__device__ __forceinline__ float b2f(unsigned short u){
  union { unsigned u; float f; } c; c.u = ((unsigned)u) << 16; return c.f;
}
__device__ __forceinline__ unsigned short f2b(float f){
  union { float f; unsigned u; } c; c.f = f;
  unsigned r = c.u + 0x7fffu + ((c.u >> 16) & 1u);
  return (unsigned short)(r >> 16);
}
__device__ __forceinline__ int clampi(int v, int lo, int hi){
  return v < lo ? lo : (v > hi ? hi : v);
}
__device__ __forceinline__ void unpack8(uint4 v, float* o){
  o[0] = b2f((unsigned short)(v.x & 0xffff)); o[1] = b2f((unsigned short)(v.x >> 16));
  o[2] = b2f((unsigned short)(v.y & 0xffff)); o[3] = b2f((unsigned short)(v.y >> 16));
  o[4] = b2f((unsigned short)(v.z & 0xffff)); o[5] = b2f((unsigned short)(v.z >> 16));
  o[6] = b2f((unsigned short)(v.w & 0xffff)); o[7] = b2f((unsigned short)(v.w >> 16));
}
__device__ __forceinline__ float fp8tof(unsigned char b){
  __hip_fp8_e4m3 q; q.__x = (__hip_fp8_storage_t)b; return (float)q;
}

// ---- K_pre: heterogeneous grid. Blocks [0,K1B): xw=x@W -> fp8 + a_src(fp16)
// + a_dst(fp32). Blocks [K1B,..): coarse 500-bin histogram of dst. ----
__global__ __launch_bounds__(256) void k_pre(
    const unsigned short* __restrict__ x, const unsigned short* __restrict__ W,
    const unsigned short* __restrict__ attS, const unsigned short* __restrict__ attD,
    const int* __restrict__ ei,
    unsigned char* __restrict__ xw8, __half* __restrict__ a_srch,
    float* __restrict__ a_dst, int* __restrict__ cc)
{
  __shared__ float Wsf[64 * 64];
  __shared__ float as_s[64];
  __shared__ float ad_s[64];
  __shared__ int hh[NBUCK];
  int t = threadIdx.x;

  if (blockIdx.x >= K1B) {
    for (int i = t; i < NBUCK; i += 256) hh[i] = 0;
    __syncthreads();
    int g = (blockIdx.x - K1B) * 256 + t;
    if (g < N_EDGESC / 4) {
      int4 d = ((const int4*)(ei + N_EDGESC))[g];
      atomicAdd(&hh[clampi(d.x, 0, N_NODESC - 1) / BSZ], 1);
      atomicAdd(&hh[clampi(d.y, 0, N_NODESC - 1) / BSZ], 1);
      atomicAdd(&hh[clampi(d.z, 0, N_NODESC - 1) / BSZ], 1);
      atomicAdd(&hh[clampi(d.w, 0, N_NODESC - 1) / BSZ], 1);
    }
    __syncthreads();
    for (int i = t; i < NBUCK; i += 256) if (hh[i]) atomicAdd(&cc[i], hh[i]);
    return;
  }

  for (int i = t; i < 4096; i += 256) Wsf[i] = b2f(W[i]);
  if (t < 64) { as_s[t] = b2f(attS[t]); ad_s[t] = b2f(attD[t]); }
  __syncthreads();

  int g    = t & 3;
  int slot = t >> 2;
  int n0 = blockIdx.x * 256 + slot * 4;

  float acc[4][16];
  #pragma unroll
  for (int j = 0; j < 4; j++)
    #pragma unroll
    for (int c = 0; c < 16; c++) acc[j][c] = 0.f;

  const float4* Ws4 = (const float4*)Wsf;
  for (int i = 0; i < 8; i++) {
    float xu[4][8];
    #pragma unroll
    for (int j = 0; j < 4; j++) {
      int n = n0 + j;
      uint4 v = make_uint4(0u,0u,0u,0u);
      if (n < N_NODESC) v = ((const uint4*)(x + (size_t)n * 64))[i];
      unpack8(v, xu[j]);
    }
    #pragma unroll
    for (int u = 0; u < 8; u++) {
      int k = i * 8 + u;
      float4 w0 = Ws4[k * 16 + g * 4 + 0];
      float4 w1 = Ws4[k * 16 + g * 4 + 1];
      float4 w2 = Ws4[k * 16 + g * 4 + 2];
      float4 w3 = Ws4[k * 16 + g * 4 + 3];
      #pragma unroll
      for (int j = 0; j < 4; j++) {
        float xk = xu[j][u];
        acc[j][ 0] += xk * w0.x; acc[j][ 1] += xk * w0.y;
        acc[j][ 2] += xk * w0.z; acc[j][ 3] += xk * w0.w;
        acc[j][ 4] += xk * w1.x; acc[j][ 5] += xk * w1.y;
        acc[j][ 6] += xk * w1.z; acc[j][ 7] += xk * w1.w;
        acc[j][ 8] += xk * w2.x; acc[j][ 9] += xk * w2.y;
        acc[j][10] += xk * w2.z; acc[j][11] += xk * w2.w;
        acc[j][12] += xk * w3.x; acc[j][13] += xk * w3.y;
        acc[j][14] += xk * w3.z; acc[j][15] += xk * w3.w;
      }
    }
  }

  #pragma unroll
  for (int j = 0; j < 4; j++) {
    int n = n0 + j;
    if (n >= N_NODESC) break;
    union { unsigned u[4]; unsigned char b[16]; } pk;
    #pragma unroll
    for (int c = 0; c < 16; c++)
      pk.b[c] = (unsigned char)__hip_fp8_e4m3(acc[j][c]).__x;
    uint4 o; o.x = pk.u[0]; o.y = pk.u[1]; o.z = pk.u[2]; o.w = pk.u[3];
    *((uint4*)(xw8 + (size_t)n * 64 + g * 16)) = o;

    #pragma unroll
    for (int hl = 0; hl < 2; hl++) {
      int h = g * 2 + hl;
      float sa = 0.f, sd = 0.f;
      #pragma unroll
      for (int c = 0; c < 8; c++) {
        sa += acc[j][hl * 8 + c] * as_s[h * 8 + c];
        sd += acc[j][hl * 8 + c] * ad_s[h * 8 + c];
      }
      a_srch[n * 8 + h] = __float2half(sa);
      a_dst[n * 8 + h] = sd;
    }
  }
}

// ---- coarse scatter (1024 thr, 8192 edges/wg): self-scan of cc -> bstart,
// LDS counting-sort by bucket, contiguous run writes via zero-based gcur ----
__global__ __launch_bounds__(1024) void k_csort(const int* __restrict__ ei,
                                                const int* __restrict__ cc,
                                                int* __restrict__ gcur,
                                                unsigned* __restrict__ cs) {
  __shared__ int bst[512];
  __shared__ int h[NBUCK], lst[NBUCK], lcur[NBUCK], gb[NBUCK];
  __shared__ int sc[512];
  __shared__ unsigned sorted[P3_EDGES];
  __shared__ unsigned short sbk[P3_EDGES];
  int t = threadIdx.x;
  int base = blockIdx.x * P3_EDGES;
  for (int i = t; i < NBUCK; i += 1024) h[i] = 0;
  int myc = 0;
  if (t < 512) { myc = (t < NBUCK) ? cc[t] : 0; bst[t] = myc; }
  __syncthreads();
  for (int off = 1; off < 512; off <<= 1) {
    int v = 0;
    if (t < 512) { v = bst[t]; if (t >= off) v += bst[t - off]; }
    __syncthreads();
    if (t < 512) bst[t] = v;
    __syncthreads();
  }
  unsigned pk[8]; int bk[8];
  #pragma unroll
  for (int k = 0; k < 8; k++) {
    int idx = base + k * 1024 + t;
    bk[k] = -1;
    if (idx < N_EDGESC) {
      int s = clampi(ei[idx], 0, N_NODESC - 1);
      int d = clampi(ei[N_EDGESC + idx], 0, N_NODESC - 1);
      int b = d / BSZ;
      pk[k] = (unsigned)s | ((unsigned)(d - b * BSZ) << 17);
      bk[k] = b;
      atomicAdd(&h[b], 1);
    }
  }
  __syncthreads();
  if (t < 512) sc[t] = (t < NBUCK) ? h[t] : 0;
  __syncthreads();
  for (int off = 1; off < 512; off <<= 1) {
    int v = 0;
    if (t < 512) { v = sc[t]; if (t >= off) v += sc[t - off]; }
    __syncthreads();
    if (t < 512) sc[t] = v;
    __syncthreads();
  }
  if (t < NBUCK) {
    int ex = sc[t] - h[t];
    lst[t] = ex; lcur[t] = ex;
    if (h[t]) gb[t] = (bst[t] - myc) + atomicAdd(&gcur[t], h[t]);
  }
  __syncthreads();
  #pragma unroll
  for (int k = 0; k < 8; k++) if (bk[k] >= 0) {
    int p = atomicAdd(&lcur[bk[k]], 1);
    sorted[p] = pk[k];
    sbk[p] = (unsigned short)bk[k];
  }
  __syncthreads();
  int cnt = N_EDGESC - base; if (cnt > P3_EDGES) cnt = P3_EDGES;
  #pragma unroll
  for (int k = 0; k < 8; k++) {
    int i = k * 1024 + t;
    if (i < cnt) {
      int b = sbk[i];
      cs[gb[b] + (i - lst[b])] = sorted[i];
    }
  }
}

// ---- K_aggf: one 1024-thread WG per bucket (200 dsts). Self-scans cc;
// counting-sorts its edges into LDS; per-dst wave aggregation.
// Main loop: full 8-edge batches, no predication; <=7-edge remainder handled
// per-edge in accumulator layout (same pattern as the overflow path). ----
__global__ __launch_bounds__(1024) void k_aggf(
    const __half* __restrict__ a_srch, const float* __restrict__ a_dst,
    const unsigned char* __restrict__ xw8, const unsigned* __restrict__ cs,
    const int* __restrict__ cc,
    const unsigned short* __restrict__ bias, unsigned short* __restrict__ nembh)
{
  __shared__ int bsc[512];
  __shared__ int lcnt[256], loff[256], lcur[256];
  __shared__ int ssrc[CAP];
  __shared__ int sbase, scnt0;
  int t = threadIdx.x;
  int b = blockIdx.x;

  int myc = 0;
  if (t < 512) { myc = (t < NBUCK) ? cc[t] : 0; bsc[t] = myc; }
  __syncthreads();
  for (int off = 1; off < 512; off <<= 1) {
    int v = 0;
    if (t < 512) { v = bsc[t]; if (t >= off) v += bsc[t - off]; }
    __syncthreads();
    if (t < 512) bsc[t] = v;
    __syncthreads();
  }
  if (t == b) { sbase = bsc[t] - myc; scnt0 = myc; }
  if (t < 256) lcnt[t] = 0;
  __syncthreads();
  int base = sbase;
  int cnt  = scnt0;
  int scnt = cnt < CAP ? cnt : CAP;

  unsigned ce[6];
  #pragma unroll
  for (int j = 0; j < 6; j++) {
    int i = t + j * 1024;
    if (i < scnt) { ce[j] = cs[base + i]; atomicAdd(&lcnt[ce[j] >> 17], 1); }
  }
  __syncthreads();
  if (t < 256) loff[t] = lcnt[t];
  __syncthreads();
  for (int off = 1; off < 256; off <<= 1) {
    int v = 0;
    if (t < 256) { v = loff[t]; if (t >= off) v += loff[t - off]; }
    __syncthreads();
    if (t < 256) loff[t] = v;
    __syncthreads();
  }
  if (t < 256) { int ex = loff[t] - lcnt[t]; loff[t] = ex; lcur[t] = ex; }
  __syncthreads();
  #pragma unroll
  for (int j = 0; j < 6; j++) {
    int i = t + j * 1024;
    if (i < scnt) {
      int p = atomicAdd(&lcur[ce[j] >> 17], 1);
      ssrc[p] = (int)(ce[j] & 0x1FFFFu);
    }
  }
  __syncthreads();

  int wv = t >> 6;
  int l  = t & 63;
  int H  = l >> 3;
  int hw = l & 7;

  for (int dl = wv; dl < BSZ; dl += 16) {
    int dst = b * BSZ + dl;
    float adH = a_dst[dst * 8 + H];
    float zs  = __half2float(a_srch[dst * 8 + H]) + adH;
    float selfw = __expf(fmaxf(zs, 0.2f * zs));
    float acc = selfw * fp8tof(xw8[(size_t)dst * 64 + l]);
    float adW = a_dst[dst * 8 + hw];

    int beg = loff[dl];
    int deg = lcnt[dl];
    int nfull = deg & ~7;
    int fend = beg + nfull;
    int end2 = beg + deg;
    float lw = 0.f, lw2 = 0.f;

    // full batches: no predication, no padding
    for (int i = beg; i < fend; i += 8) {
      int sv = ssrc[i + H];
      float av = __half2float(a_srch[sv * 8 + hw]);
      float z = av + adW;
      float w = __expf(fmaxf(z, 0.2f * z));
      lw += w;
      #pragma unroll
      for (int e = 0; e < 8; e++) {
        int   se = __builtin_amdgcn_readlane(sv, e * 8);
        float wb = __shfl(w, (e << 3) + H, 64);
        float xv = fp8tof(xw8[(size_t)se * 64 + l]);
        acc += wb * xv;
      }
    }

    // remainder (<=7 edges), accumulator layout
    for (int i = fend; i < end2; i++) {
      int sv = ssrc[i];
      float zz = __half2float(a_srch[sv * 8 + H]) + adH;
      float w = __expf(fmaxf(zz, 0.2f * zz));
      lw2 += w;
      acc += w * fp8tof(xw8[(size_t)sv * 64 + l]);
    }

    // overflow beyond LDS capacity (statistically never taken)
    for (int i = CAP; i < cnt; i++) {
      unsigned e = cs[base + i];
      if ((int)(e >> 17) != dl) continue;
      int sv = (int)(e & 0x1FFFFu);
      float zz = __half2float(a_srch[sv * 8 + H]) + adH;
      float w = __expf(fmaxf(zz, 0.2f * zz));
      lw2 += w;
      acc += w * fp8tof(xw8[(size_t)sv * 64 + l]);
    }

    lw += __shfl_xor(lw, 8, 64);
    lw += __shfl_xor(lw, 16, 64);
    lw += __shfl_xor(lw, 32, 64);
    float denom = selfw + __shfl(lw, H, 64) + lw2;

    float v = acc / denom + b2f(bias[l]);
    nembh[(size_t)dst * 64 + l] = f2b(v > 0.f ? v : 0.f);
  }
}

// ---- K6: padded gather from bf16 nemb -> fp32 out + seq_lengths tail ----
__global__ __launch_bounds__(256) void k6_gather(
    const unsigned short* __restrict__ nembh, const int* __restrict__ traj,
    const int* __restrict__ lens, float* __restrict__ out)
{
  int gid = blockIdx.x * 256 + threadIdx.x;
  if (gid < BATCHC * MAXLENC * 16) {
    int b = gid >> 15;
    int rem = gid & 32767;
    int l = rem >> 4;
    int ch = rem & 15;
    int len = clampi(lens[b], 0, MAXLENC);
    float4 val = make_float4(0.f, 0.f, 0.f, 0.f);
    if (l < len) {
      int node = clampi(traj[b * MAXLENC + l], 0, N_NODESC - 1);
      uint2 q = ((const uint2*)nembh)[(size_t)node * 16 + ch];
      val = make_float4(b2f((unsigned short)(q.x & 0xffff)),
                        b2f((unsigned short)(q.x >> 16)),
                        b2f((unsigned short)(q.y & 0xffff)),
                        b2f((unsigned short)(q.y >> 16)));
    }
    ((float4*)out)[gid] = val;
  }
  if (gid < BATCHC) {
    out[(size_t)BATCHC * MAXLENC * FEATC + gid] = (float)lens[gid];
  }
}

extern "C" void kernel_launch(void* const* d_in, const int* in_sizes, int n_in,
                              void* d_out, int out_size, void* d_ws, size_t ws_size,
                              hipStream_t stream) {
  const unsigned short* x    = (const unsigned short*)d_in[0];
  const unsigned short* W    = (const unsigned short*)d_in[1];
  const unsigned short* attS = (const unsigned short*)d_in[2];
  const unsigned short* attD = (const unsigned short*)d_in[3];
  const unsigned short* bias = (const unsigned short*)d_in[4];
  const int* ei   = (const int*)d_in[5];
  const int* traj = (const int*)d_in[6];
  const int* lens = (const int*)d_in[7];
  float* out = (float*)d_out;

  // workspace (float units, max 9.9M floats = 39.6 MB):
  //  [0, 1.6M)        xw fp8 (6.4M bytes)
  //  [3.2M, 3.6M)     a_src fp16 (800k half)
  //  [4.0M, 4.8M)     a_dst fp32
  //  [4.9M, +512)     cc (500)
  //  [+512, +1024)    gcur (500, zero-based)   -- one memset covers both
  //  [5.0M, 6.6M)     cs (packed uint, 1.6M)
  //  [6.7M, 9.9M)     nemb bf16 (6.4M ushort)
  float* F = (float*)d_ws;
  unsigned char* xw8 = (unsigned char*)d_ws;
  __half* a_srch = (__half*)(F + 3200000);
  float* a_dst   = F + 4000000;
  int* ccounts   = (int*)(F + 4900000);
  int* gcur      = (int*)(F + 4900000) + 512;
  unsigned* cs   = (unsigned*)(F + 5000000);
  unsigned short* nembh = (unsigned short*)(F + 6700000);

  hipMemsetAsync(ccounts, 0, 1024 * sizeof(int), stream);
  k_pre<<<K1B + (N_EDGESC / 4 + 255) / 256, 256, 0, stream>>>(
      x, W, attS, attD, ei, xw8, a_srch, a_dst, ccounts);
  k_csort<<<(N_EDGESC + P3_EDGES - 1) / P3_EDGES, 1024, 0, stream>>>(ei, ccounts, gcur, cs);
  k_aggf<<<NBUCK, 1024, 0, stream>>>(a_srch, a_dst, xw8, cs, ccounts, bias, nembh);
  k6_gather<<<(BATCHC * MAXLENC * 16 + 255) / 256, 256, 0, stream>>>(nembh, traj, lens, out);
}

// Round 15
// 204.797 us; speedup vs baseline: 1.4350x; 1.0253x over previous
//
#include <hip/hip_runtime.h>
#include <hip/hip_bf16.h>
#include <hip/hip_fp8.h>
#include <hip/hip_fp16.h>

#define N_NODESC 100000
#define N_EDGESC 1600000
#define FEATC 64
#define BATCHC 64
#define MAXLENC 2048
#define NBUCK 500          // 500 buckets x exactly 200 dst nodes
#define BSZ 200
#define CAP 6144           // LDS edge capacity per bucket (mean 3200)
#define P3_EDGES 8192      // edges per k_csort workgroup (1024 thr x 8)
#define K1B 391            // k_pre blocks doing the node transform

__device__ __forceinline__ float b2f(unsigned short u){
  union { unsigned u; float f; } c; c.u = ((unsigned)u) << 16; return c.f;
}
__device__ __forceinline__ unsigned short f2b(float f){
  union { float f; unsigned u; } c; c.f = f;
  unsigned r = c.u + 0x7fffu + ((c.u >> 16) & 1u);
  return (unsigned short)(r >> 16);
}
__device__ __forceinline__ int clampi(int v, int lo, int hi){
  return v < lo ? lo : (v > hi ? hi : v);
}
__device__ __forceinline__ void unpack8(uint4 v, float* o){
  o[0] = b2f((unsigned short)(v.x & 0xffff)); o[1] = b2f((unsigned short)(v.x >> 16));
  o[2] = b2f((unsigned short)(v.y & 0xffff)); o[3] = b2f((unsigned short)(v.y >> 16));
  o[4] = b2f((unsigned short)(v.z & 0xffff)); o[5] = b2f((unsigned short)(v.z >> 16));
  o[6] = b2f((unsigned short)(v.w & 0xffff)); o[7] = b2f((unsigned short)(v.w >> 16));
}
__device__ __forceinline__ float fp8tof(unsigned char b){
  __hip_fp8_e4m3 q; q.__x = (__hip_fp8_storage_t)b; return (float)q;
}

// inclusive scan of arr[0..511] (1024-thread block); wave-intrinsic, 3 barriers
__device__ __forceinline__ void scan512(int* arr, int* part, int t){
  int w = t >> 6, l = t & 63;
  if (t < 512) {
    int v = arr[t];
    #pragma unroll
    for (int off = 1; off < 64; off <<= 1) {
      int n = __shfl_up(v, off, 64);
      if (l >= off) v += n;
    }
    arr[t] = v;
    if (l == 63) part[w] = v;
  }
  __syncthreads();
  if (t < 8) {
    int p = part[t];
    #pragma unroll
    for (int off = 1; off < 8; off <<= 1) {
      int n = __shfl_up(p, off, 8);
      if (t >= off) p += n;
    }
    part[t] = p;
  }
  __syncthreads();
  if (t < 512 && w > 0) arr[t] += part[w - 1];
  __syncthreads();
}

// inclusive scan of arr[0..255] (1024-thread block); 3 barriers
__device__ __forceinline__ void scan256(int* arr, int* part, int t){
  int w = t >> 6, l = t & 63;
  if (t < 256) {
    int v = arr[t];
    #pragma unroll
    for (int off = 1; off < 64; off <<= 1) {
      int n = __shfl_up(v, off, 64);
      if (l >= off) v += n;
    }
    arr[t] = v;
    if (l == 63) part[w] = v;
  }
  __syncthreads();
  if (t < 4) {
    int p = part[t];
    #pragma unroll
    for (int off = 1; off < 4; off <<= 1) {
      int n = __shfl_up(p, off, 4);
      if (t >= off) p += n;
    }
    part[t] = p;
  }
  __syncthreads();
  if (t < 256 && w > 0) arr[t] += part[w - 1];
  __syncthreads();
}

// ---- K_pre: heterogeneous grid. Blocks [0,K1B): xw=x@W -> fp8 + a_src(fp16)
// + a_dst(fp32). Blocks [K1B,..): coarse 500-bin histogram of dst. ----
__global__ __launch_bounds__(256) void k_pre(
    const unsigned short* __restrict__ x, const unsigned short* __restrict__ W,
    const unsigned short* __restrict__ attS, const unsigned short* __restrict__ attD,
    const int* __restrict__ ei,
    unsigned char* __restrict__ xw8, __half* __restrict__ a_srch,
    float* __restrict__ a_dst, int* __restrict__ cc)
{
  __shared__ float Wsf[64 * 64];
  __shared__ float as_s[64];
  __shared__ float ad_s[64];
  __shared__ int hh[NBUCK];
  int t = threadIdx.x;

  if (blockIdx.x >= K1B) {
    for (int i = t; i < NBUCK; i += 256) hh[i] = 0;
    __syncthreads();
    int g = (blockIdx.x - K1B) * 256 + t;
    if (g < N_EDGESC / 4) {
      int4 d = ((const int4*)(ei + N_EDGESC))[g];
      atomicAdd(&hh[clampi(d.x, 0, N_NODESC - 1) / BSZ], 1);
      atomicAdd(&hh[clampi(d.y, 0, N_NODESC - 1) / BSZ], 1);
      atomicAdd(&hh[clampi(d.z, 0, N_NODESC - 1) / BSZ], 1);
      atomicAdd(&hh[clampi(d.w, 0, N_NODESC - 1) / BSZ], 1);
    }
    __syncthreads();
    for (int i = t; i < NBUCK; i += 256) if (hh[i]) atomicAdd(&cc[i], hh[i]);
    return;
  }

  for (int i = t; i < 4096; i += 256) Wsf[i] = b2f(W[i]);
  if (t < 64) { as_s[t] = b2f(attS[t]); ad_s[t] = b2f(attD[t]); }
  __syncthreads();

  int g    = t & 3;
  int slot = t >> 2;
  int n0 = blockIdx.x * 256 + slot * 4;

  float acc[4][16];
  #pragma unroll
  for (int j = 0; j < 4; j++)
    #pragma unroll
    for (int c = 0; c < 16; c++) acc[j][c] = 0.f;

  const float4* Ws4 = (const float4*)Wsf;
  for (int i = 0; i < 8; i++) {
    float xu[4][8];
    #pragma unroll
    for (int j = 0; j < 4; j++) {
      int n = n0 + j;
      uint4 v = make_uint4(0u,0u,0u,0u);
      if (n < N_NODESC) v = ((const uint4*)(x + (size_t)n * 64))[i];
      unpack8(v, xu[j]);
    }
    #pragma unroll
    for (int u = 0; u < 8; u++) {
      int k = i * 8 + u;
      float4 w0 = Ws4[k * 16 + g * 4 + 0];
      float4 w1 = Ws4[k * 16 + g * 4 + 1];
      float4 w2 = Ws4[k * 16 + g * 4 + 2];
      float4 w3 = Ws4[k * 16 + g * 4 + 3];
      #pragma unroll
      for (int j = 0; j < 4; j++) {
        float xk = xu[j][u];
        acc[j][ 0] += xk * w0.x; acc[j][ 1] += xk * w0.y;
        acc[j][ 2] += xk * w0.z; acc[j][ 3] += xk * w0.w;
        acc[j][ 4] += xk * w1.x; acc[j][ 5] += xk * w1.y;
        acc[j][ 6] += xk * w1.z; acc[j][ 7] += xk * w1.w;
        acc[j][ 8] += xk * w2.x; acc[j][ 9] += xk * w2.y;
        acc[j][10] += xk * w2.z; acc[j][11] += xk * w2.w;
        acc[j][12] += xk * w3.x; acc[j][13] += xk * w3.y;
        acc[j][14] += xk * w3.z; acc[j][15] += xk * w3.w;
      }
    }
  }

  #pragma unroll
  for (int j = 0; j < 4; j++) {
    int n = n0 + j;
    if (n >= N_NODESC) break;
    union { unsigned u[4]; unsigned char b[16]; } pk;
    #pragma unroll
    for (int c = 0; c < 16; c++)
      pk.b[c] = (unsigned char)__hip_fp8_e4m3(acc[j][c]).__x;
    uint4 o; o.x = pk.u[0]; o.y = pk.u[1]; o.z = pk.u[2]; o.w = pk.u[3];
    *((uint4*)(xw8 + (size_t)n * 64 + g * 16)) = o;

    #pragma unroll
    for (int hl = 0; hl < 2; hl++) {
      int h = g * 2 + hl;
      float sa = 0.f, sd = 0.f;
      #pragma unroll
      for (int c = 0; c < 8; c++) {
        sa += acc[j][hl * 8 + c] * as_s[h * 8 + c];
        sd += acc[j][hl * 8 + c] * ad_s[h * 8 + c];
      }
      a_srch[n * 8 + h] = __float2half(sa);
      a_dst[n * 8 + h] = sd;
    }
  }
}

// ---- coarse scatter (1024 thr, 8192 edges/wg) ----
__global__ __launch_bounds__(1024) void k_csort(const int* __restrict__ ei,
                                                const int* __restrict__ cc,
                                                int* __restrict__ gcur,
                                                unsigned* __restrict__ cs) {
  __shared__ int bst[512];
  __shared__ int h[NBUCK], lst[NBUCK], lcur[NBUCK], gb[NBUCK];
  __shared__ int sc[512];
  __shared__ int part[8];
  __shared__ unsigned sorted[P3_EDGES];
  __shared__ unsigned short sbk[P3_EDGES];
  int t = threadIdx.x;
  int base = blockIdx.x * P3_EDGES;
  for (int i = t; i < NBUCK; i += 1024) h[i] = 0;
  int myc = 0;
  if (t < 512) { myc = (t < NBUCK) ? cc[t] : 0; bst[t] = myc; }
  __syncthreads();
  scan512(bst, part, t);
  unsigned pk[8]; int bk[8];
  #pragma unroll
  for (int k = 0; k < 8; k++) {
    int idx = base + k * 1024 + t;
    bk[k] = -1;
    if (idx < N_EDGESC) {
      int s = clampi(ei[idx], 0, N_NODESC - 1);
      int d = clampi(ei[N_EDGESC + idx], 0, N_NODESC - 1);
      int b = d / BSZ;
      pk[k] = (unsigned)s | ((unsigned)(d - b * BSZ) << 17);
      bk[k] = b;
      atomicAdd(&h[b], 1);
    }
  }
  __syncthreads();
  if (t < 512) sc[t] = (t < NBUCK) ? h[t] : 0;
  __syncthreads();
  scan512(sc, part, t);
  if (t < NBUCK) {
    int ex = sc[t] - h[t];
    lst[t] = ex; lcur[t] = ex;
    if (h[t]) gb[t] = (bst[t] - myc) + atomicAdd(&gcur[t], h[t]);
  }
  __syncthreads();
  #pragma unroll
  for (int k = 0; k < 8; k++) if (bk[k] >= 0) {
    int p = atomicAdd(&lcur[bk[k]], 1);
    sorted[p] = pk[k];
    sbk[p] = (unsigned short)bk[k];
  }
  __syncthreads();
  int cnt = N_EDGESC - base; if (cnt > P3_EDGES) cnt = P3_EDGES;
  #pragma unroll
  for (int k = 0; k < 8; k++) {
    int i = k * 1024 + t;
    if (i < cnt) {
      int b = sbk[i];
      cs[gb[b] + (i - lst[b])] = sorted[i];
    }
  }
}

// ---- K_aggf: one 1024-thread WG per bucket (200 dsts). Predicated 8-edge
// batches (R11-proven) + 1-deep software prefetch of (sv, av). ----
__global__ __launch_bounds__(1024) void k_aggf(
    const __half* __restrict__ a_srch, const float* __restrict__ a_dst,
    const unsigned char* __restrict__ xw8, const unsigned* __restrict__ cs,
    const int* __restrict__ cc,
    const unsigned short* __restrict__ bias, unsigned short* __restrict__ nembh)
{
  __shared__ int bsc[512];
  __shared__ int lcnt[256], loff[256], lcur[256];
  __shared__ int part[8];
  __shared__ int ssrc[CAP];
  __shared__ int sbase, scnt0;
  int t = threadIdx.x;
  int b = blockIdx.x;

  int myc = 0;
  if (t < 512) { myc = (t < NBUCK) ? cc[t] : 0; bsc[t] = myc; }
  __syncthreads();
  scan512(bsc, part, t);
  if (t == b) { sbase = bsc[t] - myc; scnt0 = myc; }
  if (t < 256) lcnt[t] = 0;
  __syncthreads();
  int base = sbase;
  int cnt  = scnt0;
  int scnt = cnt < CAP ? cnt : CAP;

  unsigned ce[6];
  #pragma unroll
  for (int j = 0; j < 6; j++) {
    int i = t + j * 1024;
    if (i < scnt) { ce[j] = cs[base + i]; atomicAdd(&lcnt[ce[j] >> 17], 1); }
  }
  __syncthreads();
  if (t < 256) loff[t] = lcnt[t];
  __syncthreads();
  scan256(loff, part, t);
  if (t < 256) { int ex = loff[t] - lcnt[t]; loff[t] = ex; lcur[t] = ex; }
  __syncthreads();
  #pragma unroll
  for (int j = 0; j < 6; j++) {
    int i = t + j * 1024;
    if (i < scnt) {
      int p = atomicAdd(&lcur[ce[j] >> 17], 1);
      ssrc[p] = (int)(ce[j] & 0x1FFFFu);
    }
  }
  __syncthreads();

  int wv = t >> 6;
  int l  = t & 63;
  int H  = l >> 3;
  int hw = l & 7;

  for (int dl = wv; dl < BSZ; dl += 16) {
    int dst = b * BSZ + dl;
    float adH = a_dst[dst * 8 + H];
    float zs  = __half2float(a_srch[dst * 8 + H]) + adH;
    float selfw = __expf(fmaxf(zs, 0.2f * zs));
    float acc = selfw * fp8tof(xw8[(size_t)dst * 64 + l]);
    float adW = a_dst[dst * 8 + hw];

    int beg = loff[dl];
    int end2 = beg + lcnt[dl];
    float lw = 0.f, lw2 = 0.f;

    if (beg < end2) {
      int idx0 = beg + H;
      int sv = ssrc[idx0 < end2 ? idx0 : end2 - 1];
      float av = __half2float(a_srch[sv * 8 + hw]);
      for (int i = beg; i < end2; i += 8) {
        int svc = sv; float avc = av;
        bool validc = (i + H) < end2;
        if (i + 8 < end2) {
          int idx = i + 8 + H;
          sv = ssrc[idx < end2 ? idx : end2 - 1];
          av = __half2float(a_srch[sv * 8 + hw]);
        }
        float z = avc + adW;
        float w = __expf(fmaxf(z, 0.2f * z));
        w = validc ? w : 0.f;
        lw += w;
        #pragma unroll
        for (int e = 0; e < 8; e++) {
          int   se = __builtin_amdgcn_readlane(svc, e * 8);
          float wb = __shfl(w, (e << 3) + H, 64);
          float xv = fp8tof(xw8[(size_t)se * 64 + l]);
          acc += wb * xv;
        }
      }
    }

    // overflow beyond LDS capacity (statistically never taken)
    for (int i = CAP; i < cnt; i++) {
      unsigned e = cs[base + i];
      if ((int)(e >> 17) != dl) continue;
      int sv = (int)(e & 0x1FFFFu);
      float zz = __half2float(a_srch[sv * 8 + H]) + adH;
      float w = __expf(fmaxf(zz, 0.2f * zz));
      lw2 += w;
      acc += w * fp8tof(xw8[(size_t)sv * 64 + l]);
    }

    lw += __shfl_xor(lw, 8, 64);
    lw += __shfl_xor(lw, 16, 64);
    lw += __shfl_xor(lw, 32, 64);
    float denom = selfw + __shfl(lw, H, 64) + lw2;

    float v = acc / denom + b2f(bias[l]);
    nembh[(size_t)dst * 64 + l] = f2b(v > 0.f ? v : 0.f);
  }
}

// ---- K6: padded gather from bf16 nemb -> fp32 out + seq_lengths tail ----
__global__ __launch_bounds__(256) void k6_gather(
    const unsigned short* __restrict__ nembh, const int* __restrict__ traj,
    const int* __restrict__ lens, float* __restrict__ out)
{
  int gid = blockIdx.x * 256 + threadIdx.x;
  if (gid < BATCHC * MAXLENC * 16) {
    int b = gid >> 15;
    int rem = gid & 32767;
    int l = rem >> 4;
    int ch = rem & 15;
    int len = clampi(lens[b], 0, MAXLENC);
    float4 val = make_float4(0.f, 0.f, 0.f, 0.f);
    if (l < len) {
      int node = clampi(traj[b * MAXLENC + l], 0, N_NODESC - 1);
      uint2 q = ((const uint2*)nembh)[(size_t)node * 16 + ch];
      val = make_float4(b2f((unsigned short)(q.x & 0xffff)),
                        b2f((unsigned short)(q.x >> 16)),
                        b2f((unsigned short)(q.y & 0xffff)),
                        b2f((unsigned short)(q.y >> 16)));
    }
    ((float4*)out)[gid] = val;
  }
  if (gid < BATCHC) {
    out[(size_t)BATCHC * MAXLENC * FEATC + gid] = (float)lens[gid];
  }
}

extern "C" void kernel_launch(void* const* d_in, const int* in_sizes, int n_in,
                              void* d_out, int out_size, void* d_ws, size_t ws_size,
                              hipStream_t stream) {
  const unsigned short* x    = (const unsigned short*)d_in[0];
  const unsigned short* W    = (const unsigned short*)d_in[1];
  const unsigned short* attS = (const unsigned short*)d_in[2];
  const unsigned short* attD = (const unsigned short*)d_in[3];
  const unsigned short* bias = (const unsigned short*)d_in[4];
  const int* ei   = (const int*)d_in[5];
  const int* traj = (const int*)d_in[6];
  const int* lens = (const int*)d_in[7];
  float* out = (float*)d_out;

  // workspace (float units, max 9.9M floats = 39.6 MB):
  //  [0, 1.6M)        xw fp8 (6.4M bytes)
  //  [3.2M, 3.6M)     a_src fp16 (800k half)
  //  [4.0M, 4.8M)     a_dst fp32
  //  [4.9M, +512)     cc (500)
  //  [+512, +1024)    gcur (500, zero-based)   -- one memset covers both
  //  [5.0M, 6.6M)     cs (packed uint, 1.6M)
  //  [6.7M, 9.9M)     nemb bf16 (6.4M ushort)
  float* F = (float*)d_ws;
  unsigned char* xw8 = (unsigned char*)d_ws;
  __half* a_srch = (__half*)(F + 3200000);
  float* a_dst   = F + 4000000;
  int* ccounts   = (int*)(F + 4900000);
  int* gcur      = (int*)(F + 4900000) + 512;
  unsigned* cs   = (unsigned*)(F + 5000000);
  unsigned short* nembh = (unsigned short*)(F + 6700000);

  hipMemsetAsync(ccounts, 0, 1024 * sizeof(int), stream);
  k_pre<<<K1B + (N_EDGESC / 4 + 255) / 256, 256, 0, stream>>>(
      x, W, attS, attD, ei, xw8, a_srch, a_dst, ccounts);
  k_csort<<<(N_EDGESC + P3_EDGES - 1) / P3_EDGES, 1024, 0, stream>>>(ei, ccounts, gcur, cs);
  k_aggf<<<NBUCK, 1024, 0, stream>>>(a_srch, a_dst, xw8, cs, ccounts, bias, nembh);
  k6_gather<<<(BATCHC * MAXLENC * 16 + 255) / 256, 256, 0, stream>>>(nembh, traj, lens, out);
}

// Round 16
// 201.693 us; speedup vs baseline: 1.4571x; 1.0154x over previous
//
#include <hip/hip_runtime.h>
#include <hip/hip_bf16.h>
#include <hip/hip_fp8.h>
#include <hip/hip_fp16.h>

#define N_NODESC 100000
#define N_EDGESC 1600000
#define FEATC 64
#define BATCHC 64
#define MAXLENC 2048
#define NBUCK 500          // 500 buckets x exactly 200 dst nodes
#define BSZ 200
#define CAP 6144           // LDS edge capacity per bucket (mean 3200)
#define P3_EDGES 8192      // edges per k_csort workgroup (1024 thr x 8)
#define K1B 391            // k_pre blocks doing the node transform

__device__ __forceinline__ float b2f(unsigned short u){
  union { unsigned u; float f; } c; c.u = ((unsigned)u) << 16; return c.f;
}
__device__ __forceinline__ unsigned short f2b(float f){
  union { float f; unsigned u; } c; c.f = f;
  unsigned r = c.u + 0x7fffu + ((c.u >> 16) & 1u);
  return (unsigned short)(r >> 16);
}
__device__ __forceinline__ int clampi(int v, int lo, int hi){
  return v < lo ? lo : (v > hi ? hi : v);
}
__device__ __forceinline__ void unpack8(uint4 v, float* o){
  o[0] = b2f((unsigned short)(v.x & 0xffff)); o[1] = b2f((unsigned short)(v.x >> 16));
  o[2] = b2f((unsigned short)(v.y & 0xffff)); o[3] = b2f((unsigned short)(v.y >> 16));
  o[4] = b2f((unsigned short)(v.z & 0xffff)); o[5] = b2f((unsigned short)(v.z >> 16));
  o[6] = b2f((unsigned short)(v.w & 0xffff)); o[7] = b2f((unsigned short)(v.w >> 16));
}
__device__ __forceinline__ float fp8tof(unsigned char b){
  __hip_fp8_e4m3 q; q.__x = (__hip_fp8_storage_t)b; return (float)q;
}

// inclusive scan of arr[0..511] (1024-thread block); wave-intrinsic, 3 barriers
__device__ __forceinline__ void scan512(int* arr, int* part, int t){
  int w = t >> 6, l = t & 63;
  if (t < 512) {
    int v = arr[t];
    #pragma unroll
    for (int off = 1; off < 64; off <<= 1) {
      int n = __shfl_up(v, off, 64);
      if (l >= off) v += n;
    }
    arr[t] = v;
    if (l == 63) part[w] = v;
  }
  __syncthreads();
  if (t < 8) {
    int p = part[t];
    #pragma unroll
    for (int off = 1; off < 8; off <<= 1) {
      int n = __shfl_up(p, off, 8);
      if (t >= off) p += n;
    }
    part[t] = p;
  }
  __syncthreads();
  if (t < 512 && w > 0) arr[t] += part[w - 1];
  __syncthreads();
}

// inclusive scan of arr[0..255] (1024-thread block); 3 barriers
__device__ __forceinline__ void scan256(int* arr, int* part, int t){
  int w = t >> 6, l = t & 63;
  if (t < 256) {
    int v = arr[t];
    #pragma unroll
    for (int off = 1; off < 64; off <<= 1) {
      int n = __shfl_up(v, off, 64);
      if (l >= off) v += n;
    }
    arr[t] = v;
    if (l == 63) part[w] = v;
  }
  __syncthreads();
  if (t < 4) {
    int p = part[t];
    #pragma unroll
    for (int off = 1; off < 4; off <<= 1) {
      int n = __shfl_up(p, off, 4);
      if (t >= off) p += n;
    }
    part[t] = p;
  }
  __syncthreads();
  if (t < 256 && w > 0) arr[t] += part[w - 1];
  __syncthreads();
}

// ---- K_pre: heterogeneous grid. Blocks [0,K1B): xw=x@W -> fp8 + a_src(fp16)
// + a_dst(fp32). Blocks [K1B,..): coarse 500-bin histogram of dst. ----
__global__ __launch_bounds__(256) void k_pre(
    const unsigned short* __restrict__ x, const unsigned short* __restrict__ W,
    const unsigned short* __restrict__ attS, const unsigned short* __restrict__ attD,
    const int* __restrict__ ei,
    unsigned char* __restrict__ xw8, __half* __restrict__ a_srch,
    float* __restrict__ a_dst, int* __restrict__ cc)
{
  __shared__ float Wsf[64 * 64];
  __shared__ float as_s[64];
  __shared__ float ad_s[64];
  __shared__ int hh[NBUCK];
  int t = threadIdx.x;

  if (blockIdx.x >= K1B) {
    for (int i = t; i < NBUCK; i += 256) hh[i] = 0;
    __syncthreads();
    int g = (blockIdx.x - K1B) * 256 + t;
    if (g < N_EDGESC / 4) {
      int4 d = ((const int4*)(ei + N_EDGESC))[g];
      atomicAdd(&hh[clampi(d.x, 0, N_NODESC - 1) / BSZ], 1);
      atomicAdd(&hh[clampi(d.y, 0, N_NODESC - 1) / BSZ], 1);
      atomicAdd(&hh[clampi(d.z, 0, N_NODESC - 1) / BSZ], 1);
      atomicAdd(&hh[clampi(d.w, 0, N_NODESC - 1) / BSZ], 1);
    }
    __syncthreads();
    for (int i = t; i < NBUCK; i += 256) if (hh[i]) atomicAdd(&cc[i], hh[i]);
    return;
  }

  for (int i = t; i < 4096; i += 256) Wsf[i] = b2f(W[i]);
  if (t < 64) { as_s[t] = b2f(attS[t]); ad_s[t] = b2f(attD[t]); }
  __syncthreads();

  int g    = t & 3;
  int slot = t >> 2;
  int n0 = blockIdx.x * 256 + slot * 4;

  float acc[4][16];
  #pragma unroll
  for (int j = 0; j < 4; j++)
    #pragma unroll
    for (int c = 0; c < 16; c++) acc[j][c] = 0.f;

  const float4* Ws4 = (const float4*)Wsf;
  for (int i = 0; i < 8; i++) {
    float xu[4][8];
    #pragma unroll
    for (int j = 0; j < 4; j++) {
      int n = n0 + j;
      uint4 v = make_uint4(0u,0u,0u,0u);
      if (n < N_NODESC) v = ((const uint4*)(x + (size_t)n * 64))[i];
      unpack8(v, xu[j]);
    }
    #pragma unroll
    for (int u = 0; u < 8; u++) {
      int k = i * 8 + u;
      float4 w0 = Ws4[k * 16 + g * 4 + 0];
      float4 w1 = Ws4[k * 16 + g * 4 + 1];
      float4 w2 = Ws4[k * 16 + g * 4 + 2];
      float4 w3 = Ws4[k * 16 + g * 4 + 3];
      #pragma unroll
      for (int j = 0; j < 4; j++) {
        float xk = xu[j][u];
        acc[j][ 0] += xk * w0.x; acc[j][ 1] += xk * w0.y;
        acc[j][ 2] += xk * w0.z; acc[j][ 3] += xk * w0.w;
        acc[j][ 4] += xk * w1.x; acc[j][ 5] += xk * w1.y;
        acc[j][ 6] += xk * w1.z; acc[j][ 7] += xk * w1.w;
        acc[j][ 8] += xk * w2.x; acc[j][ 9] += xk * w2.y;
        acc[j][10] += xk * w2.z; acc[j][11] += xk * w2.w;
        acc[j][12] += xk * w3.x; acc[j][13] += xk * w3.y;
        acc[j][14] += xk * w3.z; acc[j][15] += xk * w3.w;
      }
    }
  }

  #pragma unroll
  for (int j = 0; j < 4; j++) {
    int n = n0 + j;
    if (n >= N_NODESC) break;
    union { unsigned u[4]; unsigned char b[16]; } pk;
    #pragma unroll
    for (int c = 0; c < 16; c++)
      pk.b[c] = (unsigned char)__hip_fp8_e4m3(acc[j][c]).__x;
    uint4 o; o.x = pk.u[0]; o.y = pk.u[1]; o.z = pk.u[2]; o.w = pk.u[3];
    *((uint4*)(xw8 + (size_t)n * 64 + g * 16)) = o;

    #pragma unroll
    for (int hl = 0; hl < 2; hl++) {
      int h = g * 2 + hl;
      float sa = 0.f, sd = 0.f;
      #pragma unroll
      for (int c = 0; c < 8; c++) {
        sa += acc[j][hl * 8 + c] * as_s[h * 8 + c];
        sd += acc[j][hl * 8 + c] * ad_s[h * 8 + c];
      }
      a_srch[n * 8 + h] = __float2half(sa);
      a_dst[n * 8 + h] = sd;
    }
  }
}

// ---- coarse scatter (1024 thr, 8192 edges/wg) ----
__global__ __launch_bounds__(1024) void k_csort(const int* __restrict__ ei,
                                                const int* __restrict__ cc,
                                                int* __restrict__ gcur,
                                                unsigned* __restrict__ cs) {
  __shared__ int bst[512];
  __shared__ int h[NBUCK], lst[NBUCK], lcur[NBUCK], gb[NBUCK];
  __shared__ int sc[512];
  __shared__ int part[8];
  __shared__ unsigned sorted[P3_EDGES];
  __shared__ unsigned short sbk[P3_EDGES];
  int t = threadIdx.x;
  int base = blockIdx.x * P3_EDGES;
  for (int i = t; i < NBUCK; i += 1024) h[i] = 0;
  int myc = 0;
  if (t < 512) { myc = (t < NBUCK) ? cc[t] : 0; bst[t] = myc; }
  __syncthreads();
  scan512(bst, part, t);
  unsigned pk[8]; int bk[8];
  #pragma unroll
  for (int k = 0; k < 8; k++) {
    int idx = base + k * 1024 + t;
    bk[k] = -1;
    if (idx < N_EDGESC) {
      int s = clampi(ei[idx], 0, N_NODESC - 1);
      int d = clampi(ei[N_EDGESC + idx], 0, N_NODESC - 1);
      int b = d / BSZ;
      pk[k] = (unsigned)s | ((unsigned)(d - b * BSZ) << 17);
      bk[k] = b;
      atomicAdd(&h[b], 1);
    }
  }
  __syncthreads();
  if (t < 512) sc[t] = (t < NBUCK) ? h[t] : 0;
  __syncthreads();
  scan512(sc, part, t);
  if (t < NBUCK) {
    int ex = sc[t] - h[t];
    lst[t] = ex; lcur[t] = ex;
    if (h[t]) gb[t] = (bst[t] - myc) + atomicAdd(&gcur[t], h[t]);
  }
  __syncthreads();
  #pragma unroll
  for (int k = 0; k < 8; k++) if (bk[k] >= 0) {
    int p = atomicAdd(&lcur[bk[k]], 1);
    sorted[p] = pk[k];
    sbk[p] = (unsigned short)bk[k];
  }
  __syncthreads();
  int cnt = N_EDGESC - base; if (cnt > P3_EDGES) cnt = P3_EDGES;
  #pragma unroll
  for (int k = 0; k < 8; k++) {
    int i = k * 1024 + t;
    if (i < cnt) {
      int b = sbk[i];
      cs[gb[b] + (i - lst[b])] = sorted[i];
    }
  }
}

// ---- K_aggf: one 1024-thread WG per bucket (200 dsts). R11-exact inner
// loop: predicated 8-edge batches, no prefetch (proven fastest). ----
__global__ __launch_bounds__(1024) void k_aggf(
    const __half* __restrict__ a_srch, const float* __restrict__ a_dst,
    const unsigned char* __restrict__ xw8, const unsigned* __restrict__ cs,
    const int* __restrict__ cc,
    const unsigned short* __restrict__ bias, unsigned short* __restrict__ nembh)
{
  __shared__ int bsc[512];
  __shared__ int lcnt[256], loff[256], lcur[256];
  __shared__ int part[8];
  __shared__ int ssrc[CAP];
  __shared__ int sbase, scnt0;
  int t = threadIdx.x;
  int b = blockIdx.x;

  int myc = 0;
  if (t < 512) { myc = (t < NBUCK) ? cc[t] : 0; bsc[t] = myc; }
  __syncthreads();
  scan512(bsc, part, t);
  if (t == b) { sbase = bsc[t] - myc; scnt0 = myc; }
  if (t < 256) lcnt[t] = 0;
  __syncthreads();
  int base = sbase;
  int cnt  = scnt0;
  int scnt = cnt < CAP ? cnt : CAP;

  unsigned ce[6];
  #pragma unroll
  for (int j = 0; j < 6; j++) {
    int i = t + j * 1024;
    if (i < scnt) { ce[j] = cs[base + i]; atomicAdd(&lcnt[ce[j] >> 17], 1); }
  }
  __syncthreads();
  if (t < 256) loff[t] = lcnt[t];
  __syncthreads();
  scan256(loff, part, t);
  if (t < 256) { int ex = loff[t] - lcnt[t]; loff[t] = ex; lcur[t] = ex; }
  __syncthreads();
  #pragma unroll
  for (int j = 0; j < 6; j++) {
    int i = t + j * 1024;
    if (i < scnt) {
      int p = atomicAdd(&lcur[ce[j] >> 17], 1);
      ssrc[p] = (int)(ce[j] & 0x1FFFFu);
    }
  }
  __syncthreads();

  int wv = t >> 6;
  int l  = t & 63;
  int H  = l >> 3;
  int hw = l & 7;

  for (int dl = wv; dl < BSZ; dl += 16) {
    int dst = b * BSZ + dl;
    float adH = a_dst[dst * 8 + H];
    float zs  = __half2float(a_srch[dst * 8 + H]) + adH;
    float selfw = __expf(fmaxf(zs, 0.2f * zs));
    float acc = selfw * fp8tof(xw8[(size_t)dst * 64 + l]);
    float adW = a_dst[dst * 8 + hw];

    int beg = loff[dl];
    int end2 = beg + lcnt[dl];
    float lw = 0.f, lw2 = 0.f;

    for (int i = beg; i < end2; i += 8) {
      int idx = i + H;
      bool valid = idx < end2;
      int sv = ssrc[valid ? idx : end2 - 1];
      float av = __half2float(a_srch[sv * 8 + hw]);
      float z = av + adW;
      float w = __expf(fmaxf(z, 0.2f * z));
      w = valid ? w : 0.f;
      lw += w;
      #pragma unroll
      for (int e = 0; e < 8; e++) {
        int   se = __builtin_amdgcn_readlane(sv, e * 8);
        float wb = __shfl(w, (e << 3) + H, 64);
        float xv = fp8tof(xw8[(size_t)se * 64 + l]);
        acc += wb * xv;
      }
    }

    // overflow beyond LDS capacity (statistically never taken)
    for (int i = CAP; i < cnt; i++) {
      unsigned e = cs[base + i];
      if ((int)(e >> 17) != dl) continue;
      int sv = (int)(e & 0x1FFFFu);
      float zz = __half2float(a_srch[sv * 8 + H]) + adH;
      float w = __expf(fmaxf(zz, 0.2f * zz));
      lw2 += w;
      acc += w * fp8tof(xw8[(size_t)sv * 64 + l]);
    }

    lw += __shfl_xor(lw, 8, 64);
    lw += __shfl_xor(lw, 16, 64);
    lw += __shfl_xor(lw, 32, 64);
    float denom = selfw + __shfl(lw, H, 64) + lw2;

    float v = acc / denom + b2f(bias[l]);
    nembh[(size_t)dst * 64 + l] = f2b(v > 0.f ? v : 0.f);
  }
}

// ---- K6: padded gather from bf16 nemb -> fp32 out + seq_lengths tail ----
__global__ __launch_bounds__(256) void k6_gather(
    const unsigned short* __restrict__ nembh, const int* __restrict__ traj,
    const int* __restrict__ lens, float* __restrict__ out)
{
  int gid = blockIdx.x * 256 + threadIdx.x;
  if (gid < BATCHC * MAXLENC * 16) {
    int b = gid >> 15;
    int rem = gid & 32767;
    int l = rem >> 4;
    int ch = rem & 15;
    int len = clampi(lens[b], 0, MAXLENC);
    float4 val = make_float4(0.f, 0.f, 0.f, 0.f);
    if (l < len) {
      int node = clampi(traj[b * MAXLENC + l], 0, N_NODESC - 1);
      uint2 q = ((const uint2*)nembh)[(size_t)node * 16 + ch];
      val = make_float4(b2f((unsigned short)(q.x & 0xffff)),
                        b2f((unsigned short)(q.x >> 16)),
                        b2f((unsigned short)(q.y & 0xffff)),
                        b2f((unsigned short)(q.y >> 16)));
    }
    ((float4*)out)[gid] = val;
  }
  if (gid < BATCHC) {
    out[(size_t)BATCHC * MAXLENC * FEATC + gid] = (float)lens[gid];
  }
}

extern "C" void kernel_launch(void* const* d_in, const int* in_sizes, int n_in,
                              void* d_out, int out_size, void* d_ws, size_t ws_size,
                              hipStream_t stream) {
  const unsigned short* x    = (const unsigned short*)d_in[0];
  const unsigned short* W    = (const unsigned short*)d_in[1];
  const unsigned short* attS = (const unsigned short*)d_in[2];
  const unsigned short* attD = (const unsigned short*)d_in[3];
  const unsigned short* bias = (const unsigned short*)d_in[4];
  const int* ei   = (const int*)d_in[5];
  const int* traj = (const int*)d_in[6];
  const int* lens = (const int*)d_in[7];
  float* out = (float*)d_out;

  // workspace (float units, max 9.9M floats = 39.6 MB):
  //  [0, 1.6M)        xw fp8 (6.4M bytes)
  //  [3.2M, 3.6M)     a_src fp16 (800k half)
  //  [4.0M, 4.8M)     a_dst fp32
  //  [4.9M, +512)     cc (500)
  //  [+512, +1024)    gcur (500, zero-based)   -- one memset covers both
  //  [5.0M, 6.6M)     cs (packed uint, 1.6M)
  //  [6.7M, 9.9M)     nemb bf16 (6.4M ushort)
  float* F = (float*)d_ws;
  unsigned char* xw8 = (unsigned char*)d_ws;
  __half* a_srch = (__half*)(F + 3200000);
  float* a_dst   = F + 4000000;
  int* ccounts   = (int*)(F + 4900000);
  int* gcur      = (int*)(F + 4900000) + 512;
  unsigned* cs   = (unsigned*)(F + 5000000);
  unsigned short* nembh = (unsigned short*)(F + 6700000);

  hipMemsetAsync(ccounts, 0, 1024 * sizeof(int), stream);
  k_pre<<<K1B + (N_EDGESC / 4 + 255) / 256, 256, 0, stream>>>(
      x, W, attS, attD, ei, xw8, a_srch, a_dst, ccounts);
  k_csort<<<(N_EDGESC + P3_EDGES - 1) / P3_EDGES, 1024, 0, stream>>>(ei, ccounts, gcur, cs);
  k_aggf<<<NBUCK, 1024, 0, stream>>>(a_srch, a_dst, xw8, cs, ccounts, bias, nembh);
  k6_gather<<<(BATCHC * MAXLENC * 16 + 255) / 256, 256, 0, stream>>>(nembh, traj, lens, out);
}